// Round 20
// baseline (572.256 us; speedup 1.0000x reference)
//
#include <hip/hip_runtime.h>
#include <hip/hip_bf16.h>

#define BN    32768
#define DD    256
#define MLPD  1024
#define TWOD  512

typedef __attribute__((ext_vector_type(8))) short short8;
typedef __attribute__((ext_vector_type(4))) float f32x4;

using bf16 = __hip_bfloat16;

__device__ __forceinline__ float bf2f(bf16 v){ return __bfloat162float(v); }
__device__ __forceinline__ bf16  f2bf(float v){ return __float2bfloat16(v); }

// async global->LDS, 16B per lane. LDS dest is wave-uniform base + lane*16.
__device__ __forceinline__ void gl_lds16(const bf16* g, bf16* l) {
    __builtin_amdgcn_global_load_lds(
        (const __attribute__((address_space(1))) void*)(g),
        (__attribute__((address_space(3))) void*)(l),
        16, 0, 0);
}

// ---------------------------------------------------------------------------
// kprep body: LDS-tiled transposes (64x64 f32 tiles) + hbf cast-copy.
// bids [0,1088).
// ---------------------------------------------------------------------------
__device__ __forceinline__ void kprep_body(
    const float* __restrict__ pre1, const float* __restrict__ pre2,
    const float* __restrict__ proj1, const float* __restrict__ proj2,
    const float* __restrict__ w10, const float* __restrict__ w11,
    const float* __restrict__ w20, const float* __restrict__ w21,
    const float* __restrict__ h,
    bf16* __restrict__ preT, bf16* __restrict__ w1T, bf16* __restrict__ w2T,
    bf16* __restrict__ hbf, int bid, char* sm)
{
    float (*ft)[68] = (float (*)[68])sm;
    const int tid = threadIdx.x;
    const int row = tid >> 2;
    const int c4  = (tid & 3) * 16;

    auto do_tile = [&](const float* src, int srcld, int r0, int c0,
                       bf16* dst, int dstld) {
        const float* sp = src + (size_t)(r0 + row)*srcld + c0 + c4;
#pragma unroll
        for (int i = 0; i < 4; i++)
            *(float4*)&ft[row][c4 + i*4] = *(const float4*)(sp + i*4);
        __syncthreads();
        bf16* dp = dst + (size_t)(c0 + row)*dstld + r0 + c4;
        short8 v0, v1;
#pragma unroll
        for (int i = 0; i < 8; i++) {
            bf16 b = f2bf(ft[c4 + i][row]);     v0[i] = *(short*)&b;
            bf16 b2 = f2bf(ft[c4 + 8 + i][row]); v1[i] = *(short*)&b2;
        }
        *(short8*)dp = v0;
        *(short8*)(dp + 8) = v1;
    };

    if (bid < 256) {
        int d = bid >> 7, r = bid & 127;
        int kt = r >> 4, jt = r & 15;           // w1: [512][1024]
        do_tile(d ? w11 : w10, 1024, kt*64, jt*64,
                w1T + (size_t)d*524288, 512);
    } else if (bid < 512) {
        int r = bid - 256;
        int d = r >> 7; r &= 127;
        int kt = r >> 3, nt = r & 7;            // w2: [1024][512]
        do_tile(d ? w21 : w20, 512, kt*64, nt*64,
                w2T + (size_t)d*524288, 1024);
    } else if (bid < 576) {
        int r = bid - 512;
        int m = r >> 4; r &= 15;
        int kt = r >> 2, et = r & 3;            // pre/proj: [256][256]
        const float* src = (m == 0) ? pre1 : (m == 1) ? pre2
                         : (m == 2) ? proj1 : proj2;
        do_tile(src, 256, kt*64, et*64, preT + (size_t)m*65536, 256);
    } else {
        const long base = (long)(bid - 576) * 16384;
#pragma unroll
        for (int it = 0; it < 16; it++) {
            long o = base + it*1024 + tid*4;
            float4 v = *(const float4*)(h + o);
            short vv[4];
#pragma unroll
            for (int j = 0; j < 4; j++) {
                bf16 b = f2bf(((const float*)&v)[j]);
                vv[j] = *(short*)&b;
            }
            *(long*)(hbf + o) = *(long*)vv;
        }
    }
}

// ---------------------------------------------------------------------------
// kxT body: transpose x[t][d][m] f32 -> token-major bf16 planes in the
// token's own output slot. 8 tokens/block.
// ---------------------------------------------------------------------------
template<int M, int ST>
__device__ __forceinline__ void kxT_body(const float* __restrict__ x,
                                         char* __restrict__ outb,
                                         int bid, float* raw)
{
    const int tid = threadIdx.x;
    const long tok0 = (long)bid * 8;
    const float4* src = (const float4*)(x + tok0*256*M);
    const int n4 = (8*256*M)/4;
    for (int i = tid; i < n4; i += 256)
        ((float4*)raw)[i] = src[i];
    __syncthreads();
    const int nOut = 8*M*32;
    for (int i = tid; i < nOut; i += 256) {
        int d8 = i & 31;
        int tm = i >> 5;
        int t = tm / M, m = tm - t*M;
        short8 v;
#pragma unroll
        for (int j = 0; j < 8; j++) {
            bf16 bv = f2bf(raw[(t*256 + d8*8 + j)*M + m]);
            v[j] = *reinterpret_cast<short*>(&bv);
        }
        *(short8*)(outb + (size_t)(tok0 + t)*ST + m*512 + d8*16) = v;
    }
}

// ---------------------------------------------------------------------------
// kpre: merged kprep + kxT<3> + kxT<5>. grid 9280 x 256.
// ---------------------------------------------------------------------------
__global__ __launch_bounds__(256) void kpre(
    const float* __restrict__ pre1, const float* __restrict__ pre2,
    const float* __restrict__ proj1, const float* __restrict__ proj2,
    const float* __restrict__ w10, const float* __restrict__ w11,
    const float* __restrict__ w20, const float* __restrict__ w21,
    const float* __restrict__ h,
    bf16* __restrict__ preT, bf16* __restrict__ w1T, bf16* __restrict__ w2T,
    bf16* __restrict__ hbf,
    const float* __restrict__ x1, char* __restrict__ x1b,
    const float* __restrict__ x2, char* __restrict__ x2b)
{
    __shared__ char sm[40960];   // union: ft 17.4K | raw3 24K | raw5 40K
    const int bid = blockIdx.x;
    if (bid < 1088)
        kprep_body(pre1, pre2, proj1, proj2, w10, w11, w20, w21, h,
                   preT, w1T, w2T, hbf, bid, sm);
    else if (bid < 5184)
        kxT_body<3, 3072>(x1, x1b, bid - 1088, (float*)sm);
    else
        kxT_body<5, 5120>(x2, x2b, bid - 5184, (float*)sm);
}

// ---------------------------------------------------------------------------
// kxg body: 32 tokens/block, 8 waves (wg = token-half, we = e-block).
// ---------------------------------------------------------------------------
template<int M, int ST, bool MOD>
__device__ __forceinline__ void kxg_body(const char* __restrict__ xtb,
                                         const bf16* __restrict__ Bmat,
                                         bf16* __restrict__ invp,
                                         const bf16* __restrict__ m2p,
                                         float* __restrict__ xout,
                                         int bid, bf16* As, bf16* Bs)
{
    const int tid = threadIdx.x;
    const int lane = tid & 63, w = tid >> 6;     // 8 waves
    const int wg = w >> 2, we = w & 3;           // token-half, e-block
    const int lh = lane >> 4, l15 = lane & 15;
    const long tok0 = (long)bid * 32;

    f32x4 acc[M][4];
#pragma unroll
    for (int m = 0; m < M; m++)
#pragma unroll
        for (int c = 0; c < 4; c++) acc[m][c] = (f32x4){0.f,0.f,0.f,0.f};

    for (int kc = 0; kc < 8; kc++) {
        for (int m = we; m < M; m += 4) {
            const char* src = xtb + (size_t)(tok0 + wg*16 + (lane >> 2))*ST
                              + m*512 + kc*64 + (lane & 3)*16;
            gl_lds16((const bf16*)src, As + (wg*M + m)*512);
        }
#pragma unroll
        for (int j = 0; j < 2; j++) {
            int row = (w*2 + j)*16 + (lane >> 2);
            gl_lds16(Bmat + row*256 + kc*32 + (lane & 3)*8,
                     Bs + (w*2 + j)*512);
        }
        __syncthreads();
        short8 a[M], b[4];
#pragma unroll
        for (int m = 0; m < M; m++)
            a[m] = *(const short8*)&As[(wg*M + m)*512 + l15*32 + lh*8];
#pragma unroll
        for (int ct = 0; ct < 4; ct++)
            b[ct] = *(const short8*)&Bs[(we*64 + ct*16 + l15)*32 + lh*8];
#pragma unroll
        for (int m = 0; m < M; m++)
#pragma unroll
            for (int ct = 0; ct < 4; ct++)
                acc[m][ct] = __builtin_amdgcn_mfma_f32_16x16x32_bf16(a[m], b[ct], acc[m][ct], 0, 0, 0);
        __syncthreads();
    }

    if constexpr (!MOD) {
#pragma unroll
        for (int ct = 0; ct < 4; ct++) {
#pragma unroll
            for (int i = 0; i < 4; i++) {
                long t = tok0 + wg*16 + lh*4 + i;
                int e = we*64 + ct*16 + l15;
                float s = 0.f;
#pragma unroll
                for (int m = 0; m < M; m++) { float p = acc[m][ct][i]; s += p*p; }
                invp[t*256 + e] = f2bf(sqrtf(s));
            }
        }
    } else {
        // phase A: fold residual (bf16 xT, L2-hot) + m2 scale. READS ONLY.
#pragma unroll
        for (int ct = 0; ct < 4; ct++) {
#pragma unroll
            for (int i = 0; i < 4; i++) {
                long t = tok0 + wg*16 + lh*4 + i;
                int e = we*64 + ct*16 + l15;
                float m2v = bf2f(m2p[t*256 + e]);
                const char* slot = xtb + (size_t)t*ST + e*2;
#pragma unroll
                for (int m = 0; m < M; m++) {
                    float xv = bf2f(*(const bf16*)(slot + m*512));
                    acc[m][ct][i] = xv + acc[m][ct][i]*m2v;
                }
            }
        }
        __syncthreads();
        // phase B: writes only
#pragma unroll
        for (int ct = 0; ct < 4; ct++) {
#pragma unroll
            for (int i = 0; i < 4; i++) {
                long t = tok0 + wg*16 + lh*4 + i;
                int e = we*64 + ct*16 + l15;
#pragma unroll
                for (int m = 0; m < M; m++) {
                    long gi = (t*256 + e)*(long)M + m;
                    xout[gi] = acc[m][ct][i];
                }
            }
        }
    }
}

// ---------------------------------------------------------------------------
// kxgi: merged inv pass. grid 2048: [0,1024) = x1 (M=3), rest x2 (M=5).
// ---------------------------------------------------------------------------
__global__ __launch_bounds__(512) void kxgi(const char* __restrict__ x1b,
                                            const char* __restrict__ x2b,
                                            const bf16* __restrict__ preT,
                                            bf16* __restrict__ invm2)
{
    __shared__ bf16 As[2*5*512];
    __shared__ bf16 Bs[8192];
    const int bid = blockIdx.x;
    if (bid < 1024)
        kxg_body<3, 3072, false>(x1b, preT, invm2, nullptr, nullptr,
                                 bid, As, Bs);
    else
        kxg_body<5, 5120, false>(x2b, preT + 65536,
                                 invm2 + (size_t)BN*256, nullptr, nullptr,
                                 bid - 1024, As, Bs);
}

// ---------------------------------------------------------------------------
// kxgm: merged mod pass. grid 2048: [0,1024) = x1 (M=3), rest x2 (M=5).
// ---------------------------------------------------------------------------
__global__ __launch_bounds__(512) void kxgm(const char* __restrict__ x1b,
                                            const char* __restrict__ x2b,
                                            const bf16* __restrict__ projT,
                                            const bf16* __restrict__ m2ws,
                                            float* __restrict__ x1out,
                                            float* __restrict__ x2out)
{
    __shared__ bf16 As[2*5*512];
    __shared__ bf16 Bs[8192];
    const int bid = blockIdx.x;
    if (bid < 1024)
        kxg_body<3, 3072, true>(x1b, projT, nullptr, m2ws, x1out,
                                bid, As, Bs);
    else
        kxg_body<5, 5120, true>(x2b, projT + 65536, nullptr,
                                m2ws + (size_t)BN*256, x2out,
                                bid - 1024, As, Bs);
}

// ---------------------------------------------------------------------------
// kmlp1: 512-thr / 8-wave blocks, 128x256 tile, BK=32, single-buffer LDS,
// R4-exact sync. C[t,j] over A=[hbf|inv_d] (K=512), B=w1T_d.
// Epilogue: bias+silu -> hid slots / hid1b.
// grid 2048 = 2 d x 256 mtile x 4 ntile, XCD swizzle q=256.
// ---------------------------------------------------------------------------
__global__ __launch_bounds__(512) void kmlp1(const bf16* __restrict__ hbf,
                                             const bf16* __restrict__ invws,
                                             const bf16* __restrict__ w1T,
                                             const float* __restrict__ b1_0,
                                             const float* __restrict__ b1_1,
                                             char* __restrict__ x1b,
                                             char* __restrict__ x2b,
                                             bf16* __restrict__ hid1b)
{
    __shared__ bf16 As[128*32];   // [128 t][32 k]
    __shared__ bf16 Bs[256*32];   // [256 j][32 k]
    const int tid = threadIdx.x;
    const int lane = tid & 63, w = tid >> 6;     // 8 waves
    const int wr = w >> 2, wc = w & 3;           // 2 row-blocks x 4 col-blocks
    const int lh = lane >> 4, l15 = lane & 15;

    const int bid   = ((blockIdx.x & 7) << 8) | (blockIdx.x >> 3);  // q=256
    const int d     = bid >> 10;
    const int r     = bid & 1023;
    const int mtile = r >> 2;
    const int ntile = r & 3;
    const long tok0 = (long)mtile * 128;
    const int  j0   = ntile * 256;

    const bf16* Ahb = hbf   + (size_t)tok0 * 256;
    const bf16* Ain = invws + (size_t)d * BN * 256 + (size_t)tok0 * 256;
    const bf16* Bw  = w1T   + (size_t)d * MLPD * TWOD;
    const float* b1 = d ? b1_1 : b1_0;

    const int srow = tid >> 2;          // 0..127
    const int scol = (tid & 3) * 8;     // bf16 offset of 16B

    f32x4 acc[4][4];
#pragma unroll
    for (int ai = 0; ai < 4; ai++)
#pragma unroll
        for (int bj = 0; bj < 4; bj++) acc[ai][bj] = (f32x4){0.f,0.f,0.f,0.f};

    for (int kc = 0; kc < 16; kc++) {
        {
            const bf16* src = (kc < 8)
                ? Ahb + (size_t)srow*256 + kc*32 + scol
                : Ain + (size_t)srow*256 + (kc - 8)*32 + scol;
            gl_lds16(src, As + w*512);
        }
#pragma unroll
        for (int i = 0; i < 2; i++) {
            gl_lds16(Bw + (size_t)(j0 + i*128 + srow)*512 + kc*32 + scol,
                     Bs + i*4096 + w*512);
        }
        __syncthreads();
        short8 a[4], b[4];
#pragma unroll
        for (int ai = 0; ai < 4; ai++)
            a[ai] = *(const short8*)&As[(wr*64 + ai*16 + l15)*32 + lh*8];
#pragma unroll
        for (int bj = 0; bj < 4; bj++)
            b[bj] = *(const short8*)&Bs[(wc*64 + bj*16 + l15)*32 + lh*8];
#pragma unroll
        for (int ai = 0; ai < 4; ai++)
#pragma unroll
            for (int bj = 0; bj < 4; bj++)
                acc[ai][bj] = __builtin_amdgcn_mfma_f32_16x16x32_bf16(a[ai], b[bj], acc[ai][bj], 0, 0, 0);
        __syncthreads();
    }

#pragma unroll
    for (int ai = 0; ai < 4; ai++) {
#pragma unroll
        for (int bj = 0; bj < 4; bj++) {
#pragma unroll
            for (int i = 0; i < 4; i++) {
                long t = tok0 + wr*64 + ai*16 + lh*4 + i;
                int  j = j0 + wc*64 + bj*16 + l15;
                float v = acc[ai][bj][i] + b1[j];
                float s = v / (1.0f + __expf(-v));
                bf16 sb = f2bf(s);
                if (d == 0) {
                    *(bf16*)(x2b + (size_t)t*5120 + 2560 + j*2) = sb;
                } else {
                    if (j < 768) *(bf16*)(x1b + (size_t)t*3072 + 1536 + j*2) = sb;
                    else         hid1b[t*256 + (j - 768)] = sb;
                }
            }
        }
    }
}

// ---------------------------------------------------------------------------
// kmlp2: 512-thr / 8-wave blocks, 128x256 tile, BK=32, single-buffer,
// R4-exact sync. grid 512, PERFECTLY BALANCED: slot 0 = m1 (K=2048, 64
// iters) -> h_new; slot 1 = BOTH m2 degrees (2 x 32 iters, mid-kernel
// epilogue between) -> m2ws. Every block = 64 iter-units, 2 blocks/CU =
// exactly one occupancy round. XCD swizzle q=64 keeps (mtile, both slots)
// on one XCD for L2 A-panel sharing.
// hid0: x2 slot gap. hid1: x1 slot gap (kk<24) + hid1b ws (kk>=24).
// ---------------------------------------------------------------------------
__global__ __launch_bounds__(512) void kmlp2(const char* __restrict__ x1b,
                                             const char* __restrict__ x2b,
                                             const bf16* __restrict__ hid1b,
                                             const bf16* __restrict__ w2T,
                                             const float* __restrict__ b2_0,
                                             const float* __restrict__ b2_1,
                                             const bf16* __restrict__ hbf,
                                             bf16* __restrict__ m2ws,
                                             float* __restrict__ hout)
{
    __shared__ bf16 As[128*32];
    __shared__ bf16 Bs[256*32];
    const int tid = threadIdx.x;
    const int lane = tid & 63, w = tid >> 6;
    const int wr = w >> 2, wc = w & 3;
    const int lh = lane >> 4, l15 = lane & 15;

    const int nb = blockIdx.x;                  // 512
    const int b2 = (nb & 7)*64 + (nb >> 3);     // bijective, q=64
    const int mtile = b2 >> 1;
    const int slot  = b2 & 1;                   // 0 = m1, 1 = m2 both degrees
    const long tok0 = (long)mtile * 128;

    const int srow = tid >> 2;
    const int scol = (tid & 3) * 8;

    f32x4 acc[4][4];

    auto zero_acc = [&]() {
#pragma unroll
        for (int ai = 0; ai < 4; ai++)
#pragma unroll
            for (int bj = 0; bj < 4; bj++) acc[ai][bj] = (f32x4){0.f,0.f,0.f,0.f};
    };
    auto kstep = [&](int d, int kk, int n0) {
        {
            const bf16* src;
            if (d == 0)
                src = (const bf16*)(x2b + (size_t)(tok0 + srow)*5120 + 2560
                                    + kk*64 + (tid & 3)*16);
            else if (kk < 24)
                src = (const bf16*)(x1b + (size_t)(tok0 + srow)*3072 + 1536
                                    + kk*64 + (tid & 3)*16);
            else
                src = hid1b + (size_t)(tok0 + srow)*256 + (kk - 24)*32 + scol;
            gl_lds16(src, As + w*512);
        }
        const bf16* Bw = w2T + (size_t)d * TWOD * MLPD;
#pragma unroll
        for (int i = 0; i < 2; i++) {
            gl_lds16(Bw + (size_t)(n0 + i*128 + srow)*MLPD + kk*32 + scol,
                     Bs + i*4096 + w*512);
        }
        __syncthreads();
        short8 a[4], b[4];
#pragma unroll
        for (int ai = 0; ai < 4; ai++)
            a[ai] = *(const short8*)&As[(wr*64 + ai*16 + l15)*32 + lh*8];
#pragma unroll
        for (int bj = 0; bj < 4; bj++)
            b[bj] = *(const short8*)&Bs[(wc*64 + bj*16 + l15)*32 + lh*8];
#pragma unroll
        for (int ai = 0; ai < 4; ai++)
#pragma unroll
            for (int bj = 0; bj < 4; bj++)
                acc[ai][bj] = __builtin_amdgcn_mfma_f32_16x16x32_bf16(a[ai], b[bj], acc[ai][bj], 0, 0, 0);
        __syncthreads();
    };

    if (slot == 0) {
        // m1: cols [0,256), K = 2048 over both degrees
        zero_acc();
        for (int it = 0; it < 64; it++)
            kstep(it >> 5, it & 31, 0);
#pragma unroll
        for (int ai = 0; ai < 4; ai++) {
#pragma unroll
            for (int bj = 0; bj < 4; bj++) {
#pragma unroll
                for (int i = 0; i < 4; i++) {
                    long t = tok0 + wr*64 + ai*16 + lh*4 + i;
                    int  n = wc*64 + bj*16 + l15;
                    float v = acc[ai][bj][i] + b2_0[n] + b2_1[n];
                    hout[t*256 + n] = bf2f(hbf[t*256 + n]) + v;
                }
            }
        }
    } else {
        // m2: cols [256,512), each degree separately (32 iters each)
#pragma unroll
        for (int d = 0; d < 2; d++) {
            zero_acc();
            for (int kk = 0; kk < 32; kk++)
                kstep(d, kk, 256);
            const float* b2 = d ? b2_1 : b2_0;
#pragma unroll
            for (int ai = 0; ai < 4; ai++) {
#pragma unroll
                for (int bj = 0; bj < 4; bj++) {
#pragma unroll
                    for (int i = 0; i < 4; i++) {
                        long t = tok0 + wr*64 + ai*16 + lh*4 + i;
                        int  n = 256 + wc*64 + bj*16 + l15;
                        float v = acc[ai][bj][i] + b2[n];
                        m2ws[(size_t)d * BN * 256 + t*256 + (n - 256)] = f2bf(v);
                    }
                }
            }
        }
    }
}

// ---------------------------------------------------------------------------
extern "C" void kernel_launch(void* const* d_in, const int* in_sizes, int n_in,
                              void* d_out, int out_size, void* d_ws, size_t ws_size,
                              hipStream_t stream)
{
    const float* h     = (const float*)d_in[0];
    const float* x1    = (const float*)d_in[1];
    const float* x2    = (const float*)d_in[2];
    const float* proj1 = (const float*)d_in[3];
    const float* proj2 = (const float*)d_in[4];
    const float* pre1  = (const float*)d_in[5];
    const float* pre2  = (const float*)d_in[6];
    const float* w10   = (const float*)d_in[7];
    const float* b10   = (const float*)d_in[8];
    const float* w20   = (const float*)d_in[9];
    const float* b20   = (const float*)d_in[10];
    const float* w11   = (const float*)d_in[11];
    const float* b11   = (const float*)d_in[12];
    const float* w21   = (const float*)d_in[13];
    const float* b21   = (const float*)d_in[14];

    // ws (bf16 elems): preT[131072] projT[131072] w1T[1048576] w2T[1048576]
    //   hbf[8388608] invm2[16777216] hid1b[8388608] -> 35,913,728 = 68.5 MiB
    bf16* preT  = (bf16*)d_ws;
    bf16* projT = preT  + 131072;
    bf16* w1T   = projT + 131072;
    bf16* w2T   = w1T   + 1048576;
    bf16* hbf   = w2T   + 1048576;
    bf16* invm2 = hbf   + 8388608;   // inv (kxgi->kmlp1), then m2 (kmlp2->kxgm)
    bf16* hid1b = invm2 + 16777216;  // hid1 cols 768..1023
    if (ws_size < (size_t)35913728 * 2) return;

    float* hout  = (float*)d_out;
    float* x1out = hout + (size_t)8388608;   // 96 MiB region, 3072 B/token
    float* x2out = hout + (size_t)33554432;  // 160 MiB region, 5120 B/token
    char* x1b = (char*)x1out;  // slot: [xT1 1536B][hid1 j<768 1536B]
    char* x2b = (char*)x2out;  // slot: [xT2 2560B][hid0 2048B][pad 512B]

    kpre<<<9280, 256, 0, stream>>>(pre1, pre2, proj1, proj2, w10, w11, w20, w21,
                                   h, preT, w1T, w2T, hbf, x1, x1b, x2, x2b);
    kxgi<<<2048, 512, 0, stream>>>(x1b, x2b, preT, invm2);
    kmlp1<<<2048, 512, 0, stream>>>(hbf, invm2, w1T, b10, b11, x1b, x2b, hid1b);
    kmlp2<<<512, 512, 0, stream>>>(x1b, x2b, hid1b, w2T, b20, b21, hbf, invm2, hout);
    kxgm<<<2048, 512, 0, stream>>>(x1b, x2b, projT, invm2, x1out, x2out);
}

// Round 21
// 546.040 us; speedup vs baseline: 1.0480x; 1.0480x over previous
//
#include <hip/hip_runtime.h>
#include <hip/hip_bf16.h>

#define BN    32768
#define DD    256
#define MLPD  1024
#define TWOD  512

typedef __attribute__((ext_vector_type(8))) short short8;
typedef __attribute__((ext_vector_type(4))) float f32x4;

using bf16 = __hip_bfloat16;

__device__ __forceinline__ float bf2f(bf16 v){ return __bfloat162float(v); }
__device__ __forceinline__ bf16  f2bf(float v){ return __float2bfloat16(v); }

// async global->LDS, 16B per lane. LDS dest is wave-uniform base + lane*16.
__device__ __forceinline__ void gl_lds16(const bf16* g, bf16* l) {
    __builtin_amdgcn_global_load_lds(
        (const __attribute__((address_space(1))) void*)(g),
        (__attribute__((address_space(3))) void*)(l),
        16, 0, 0);
}

// ---------------------------------------------------------------------------
// kprep body: LDS-tiled transposes (64x64 f32 tiles) + hbf cast-copy.
// bids [0,1088).
// ---------------------------------------------------------------------------
__device__ __forceinline__ void kprep_body(
    const float* __restrict__ pre1, const float* __restrict__ pre2,
    const float* __restrict__ proj1, const float* __restrict__ proj2,
    const float* __restrict__ w10, const float* __restrict__ w11,
    const float* __restrict__ w20, const float* __restrict__ w21,
    const float* __restrict__ h,
    bf16* __restrict__ preT, bf16* __restrict__ w1T, bf16* __restrict__ w2T,
    bf16* __restrict__ hbf, int bid, char* sm)
{
    float (*ft)[68] = (float (*)[68])sm;
    const int tid = threadIdx.x;
    const int row = tid >> 2;
    const int c4  = (tid & 3) * 16;

    auto do_tile = [&](const float* src, int srcld, int r0, int c0,
                       bf16* dst, int dstld) {
        const float* sp = src + (size_t)(r0 + row)*srcld + c0 + c4;
#pragma unroll
        for (int i = 0; i < 4; i++)
            *(float4*)&ft[row][c4 + i*4] = *(const float4*)(sp + i*4);
        __syncthreads();
        bf16* dp = dst + (size_t)(c0 + row)*dstld + r0 + c4;
        short8 v0, v1;
#pragma unroll
        for (int i = 0; i < 8; i++) {
            bf16 b = f2bf(ft[c4 + i][row]);     v0[i] = *(short*)&b;
            bf16 b2 = f2bf(ft[c4 + 8 + i][row]); v1[i] = *(short*)&b2;
        }
        *(short8*)dp = v0;
        *(short8*)(dp + 8) = v1;
    };

    if (bid < 256) {
        int d = bid >> 7, r = bid & 127;
        int kt = r >> 4, jt = r & 15;           // w1: [512][1024]
        do_tile(d ? w11 : w10, 1024, kt*64, jt*64,
                w1T + (size_t)d*524288, 512);
    } else if (bid < 512) {
        int r = bid - 256;
        int d = r >> 7; r &= 127;
        int kt = r >> 3, nt = r & 7;            // w2: [1024][512]
        do_tile(d ? w21 : w20, 512, kt*64, nt*64,
                w2T + (size_t)d*524288, 1024);
    } else if (bid < 576) {
        int r = bid - 512;
        int m = r >> 4; r &= 15;
        int kt = r >> 2, et = r & 3;            // pre/proj: [256][256]
        const float* src = (m == 0) ? pre1 : (m == 1) ? pre2
                         : (m == 2) ? proj1 : proj2;
        do_tile(src, 256, kt*64, et*64, preT + (size_t)m*65536, 256);
    } else {
        const long base = (long)(bid - 576) * 16384;
#pragma unroll
        for (int it = 0; it < 16; it++) {
            long o = base + it*1024 + tid*4;
            float4 v = *(const float4*)(h + o);
            short vv[4];
#pragma unroll
            for (int j = 0; j < 4; j++) {
                bf16 b = f2bf(((const float*)&v)[j]);
                vv[j] = *(short*)&b;
            }
            *(long*)(hbf + o) = *(long*)vv;
        }
    }
}

// ---------------------------------------------------------------------------
// kxT body: transpose x[t][d][m] f32 -> token-major bf16 planes in the
// token's own output slot. 8 tokens/block.
// ---------------------------------------------------------------------------
template<int M, int ST>
__device__ __forceinline__ void kxT_body(const float* __restrict__ x,
                                         char* __restrict__ outb,
                                         int bid, float* raw)
{
    const int tid = threadIdx.x;
    const long tok0 = (long)bid * 8;
    const float4* src = (const float4*)(x + tok0*256*M);
    const int n4 = (8*256*M)/4;
    for (int i = tid; i < n4; i += 256)
        ((float4*)raw)[i] = src[i];
    __syncthreads();
    const int nOut = 8*M*32;
    for (int i = tid; i < nOut; i += 256) {
        int d8 = i & 31;
        int tm = i >> 5;
        int t = tm / M, m = tm - t*M;
        short8 v;
#pragma unroll
        for (int j = 0; j < 8; j++) {
            bf16 bv = f2bf(raw[(t*256 + d8*8 + j)*M + m]);
            v[j] = *reinterpret_cast<short*>(&bv);
        }
        *(short8*)(outb + (size_t)(tok0 + t)*ST + m*512 + d8*16) = v;
    }
}

// ---------------------------------------------------------------------------
// kpre: merged kprep + kxT<3> + kxT<5>. grid 9280 x 256.
// ---------------------------------------------------------------------------
__global__ __launch_bounds__(256) void kpre(
    const float* __restrict__ pre1, const float* __restrict__ pre2,
    const float* __restrict__ proj1, const float* __restrict__ proj2,
    const float* __restrict__ w10, const float* __restrict__ w11,
    const float* __restrict__ w20, const float* __restrict__ w21,
    const float* __restrict__ h,
    bf16* __restrict__ preT, bf16* __restrict__ w1T, bf16* __restrict__ w2T,
    bf16* __restrict__ hbf,
    const float* __restrict__ x1, char* __restrict__ x1b,
    const float* __restrict__ x2, char* __restrict__ x2b)
{
    __shared__ char sm[40960];   // union: ft 17.4K | raw3 24K | raw5 40K
    const int bid = blockIdx.x;
    if (bid < 1088)
        kprep_body(pre1, pre2, proj1, proj2, w10, w11, w20, w21, h,
                   preT, w1T, w2T, hbf, bid, sm);
    else if (bid < 5184)
        kxT_body<3, 3072>(x1, x1b, bid - 1088, (float*)sm);
    else
        kxT_body<5, 5120>(x2, x2b, bid - 5184, (float*)sm);
}

// ---------------------------------------------------------------------------
// kxg body: 32 tokens/block, 8 waves (wg = token-half, we = e-block).
// A = xT planes per half (gl_lds16), B staged once per chunk, shared halves.
// MOD=false: inv[t][e] = sqrt(sum_m acc^2).
// MOD=true : xout = bf16(x) + acc*m2 (phase A fold reads-only / full-drain
//            barrier / phase B writes-only; own-slot in-place safe).
// ---------------------------------------------------------------------------
template<int M, int ST, bool MOD>
__device__ __forceinline__ void kxg_body(const char* __restrict__ xtb,
                                         const bf16* __restrict__ Bmat,
                                         bf16* __restrict__ invp,
                                         const bf16* __restrict__ m2p,
                                         float* __restrict__ xout,
                                         int bid, bf16* As, bf16* Bs)
{
    const int tid = threadIdx.x;
    const int lane = tid & 63, w = tid >> 6;     // 8 waves
    const int wg = w >> 2, we = w & 3;           // token-half, e-block
    const int lh = lane >> 4, l15 = lane & 15;
    const long tok0 = (long)bid * 32;

    f32x4 acc[M][4];
#pragma unroll
    for (int m = 0; m < M; m++)
#pragma unroll
        for (int c = 0; c < 4; c++) acc[m][c] = (f32x4){0.f,0.f,0.f,0.f};

    for (int kc = 0; kc < 8; kc++) {
        for (int m = we; m < M; m += 4) {
            const char* src = xtb + (size_t)(tok0 + wg*16 + (lane >> 2))*ST
                              + m*512 + kc*64 + (lane & 3)*16;
            gl_lds16((const bf16*)src, As + (wg*M + m)*512);
        }
#pragma unroll
        for (int j = 0; j < 2; j++) {
            int row = (w*2 + j)*16 + (lane >> 2);
            gl_lds16(Bmat + row*256 + kc*32 + (lane & 3)*8,
                     Bs + (w*2 + j)*512);
        }
        __syncthreads();
        short8 a[M], b[4];
#pragma unroll
        for (int m = 0; m < M; m++)
            a[m] = *(const short8*)&As[(wg*M + m)*512 + l15*32 + lh*8];
#pragma unroll
        for (int ct = 0; ct < 4; ct++)
            b[ct] = *(const short8*)&Bs[(we*64 + ct*16 + l15)*32 + lh*8];
#pragma unroll
        for (int m = 0; m < M; m++)
#pragma unroll
            for (int ct = 0; ct < 4; ct++)
                acc[m][ct] = __builtin_amdgcn_mfma_f32_16x16x32_bf16(a[m], b[ct], acc[m][ct], 0, 0, 0);
        __syncthreads();
    }

    if constexpr (!MOD) {
#pragma unroll
        for (int ct = 0; ct < 4; ct++) {
#pragma unroll
            for (int i = 0; i < 4; i++) {
                long t = tok0 + wg*16 + lh*4 + i;
                int e = we*64 + ct*16 + l15;
                float s = 0.f;
#pragma unroll
                for (int m = 0; m < M; m++) { float p = acc[m][ct][i]; s += p*p; }
                invp[t*256 + e] = f2bf(sqrtf(s));
            }
        }
    } else {
        // phase A: fold residual (bf16 xT, L2-hot) + m2 scale. READS ONLY.
#pragma unroll
        for (int ct = 0; ct < 4; ct++) {
#pragma unroll
            for (int i = 0; i < 4; i++) {
                long t = tok0 + wg*16 + lh*4 + i;
                int e = we*64 + ct*16 + l15;
                float m2v = bf2f(m2p[t*256 + e]);
                const char* slot = xtb + (size_t)t*ST + e*2;
#pragma unroll
                for (int m = 0; m < M; m++) {
                    float xv = bf2f(*(const bf16*)(slot + m*512));
                    acc[m][ct][i] = xv + acc[m][ct][i]*m2v;
                }
            }
        }
        __syncthreads();
        // phase B: writes only
#pragma unroll
        for (int ct = 0; ct < 4; ct++) {
#pragma unroll
            for (int i = 0; i < 4; i++) {
                long t = tok0 + wg*16 + lh*4 + i;
                int e = we*64 + ct*16 + l15;
#pragma unroll
                for (int m = 0; m < M; m++) {
                    long gi = (t*256 + e)*(long)M + m;
                    xout[gi] = acc[m][ct][i];
                }
            }
        }
    }
}

// ---------------------------------------------------------------------------
// kxgi: merged inv pass. grid 2048: [0,1024) = x1 (M=3), rest x2 (M=5).
// ---------------------------------------------------------------------------
__global__ __launch_bounds__(512) void kxgi(const char* __restrict__ x1b,
                                            const char* __restrict__ x2b,
                                            const bf16* __restrict__ preT,
                                            bf16* __restrict__ invm2)
{
    __shared__ bf16 As[2*5*512];
    __shared__ bf16 Bs[8192];
    const int bid = blockIdx.x;
    if (bid < 1024)
        kxg_body<3, 3072, false>(x1b, preT, invm2, nullptr, nullptr,
                                 bid, As, Bs);
    else
        kxg_body<5, 5120, false>(x2b, preT + 65536,
                                 invm2 + (size_t)BN*256, nullptr, nullptr,
                                 bid - 1024, As, Bs);
}

// ---------------------------------------------------------------------------
// kxgm: merged mod pass. grid 2048: [0,1024) = x1 (M=3), rest x2 (M=5).
// ---------------------------------------------------------------------------
__global__ __launch_bounds__(512) void kxgm(const char* __restrict__ x1b,
                                            const char* __restrict__ x2b,
                                            const bf16* __restrict__ projT,
                                            const bf16* __restrict__ m2ws,
                                            float* __restrict__ x1out,
                                            float* __restrict__ x2out)
{
    __shared__ bf16 As[2*5*512];
    __shared__ bf16 Bs[8192];
    const int bid = blockIdx.x;
    if (bid < 1024)
        kxg_body<3, 3072, true>(x1b, projT, nullptr, m2ws, x1out,
                                bid, As, Bs);
    else
        kxg_body<5, 5120, true>(x2b, projT + 65536, nullptr,
                                m2ws + (size_t)BN*256, x2out,
                                bid - 1024, As, Bs);
}

// ---------------------------------------------------------------------------
// kmlp1: 512-thr / 8-wave blocks, 128x256 tile, BK=32, single-buffer LDS,
// R4-exact sync. C[t,j] over A=[hbf|inv_d] (K=512), B=w1T_d.
// Epilogue: bias+silu -> hid slots / hid1b.
// grid 2048 = 2 d x 256 mtile x 4 ntile, XCD swizzle q=256.
// ---------------------------------------------------------------------------
__global__ __launch_bounds__(512) void kmlp1(const bf16* __restrict__ hbf,
                                             const bf16* __restrict__ invws,
                                             const bf16* __restrict__ w1T,
                                             const float* __restrict__ b1_0,
                                             const float* __restrict__ b1_1,
                                             char* __restrict__ x1b,
                                             char* __restrict__ x2b,
                                             bf16* __restrict__ hid1b)
{
    __shared__ bf16 As[128*32];   // [128 t][32 k]
    __shared__ bf16 Bs[256*32];   // [256 j][32 k]
    const int tid = threadIdx.x;
    const int lane = tid & 63, w = tid >> 6;     // 8 waves
    const int wr = w >> 2, wc = w & 3;           // 2 row-blocks x 4 col-blocks
    const int lh = lane >> 4, l15 = lane & 15;

    const int bid   = ((blockIdx.x & 7) << 8) | (blockIdx.x >> 3);  // q=256
    const int d     = bid >> 10;
    const int r     = bid & 1023;
    const int mtile = r >> 2;
    const int ntile = r & 3;
    const long tok0 = (long)mtile * 128;
    const int  j0   = ntile * 256;

    const bf16* Ahb = hbf   + (size_t)tok0 * 256;
    const bf16* Ain = invws + (size_t)d * BN * 256 + (size_t)tok0 * 256;
    const bf16* Bw  = w1T   + (size_t)d * MLPD * TWOD;
    const float* b1 = d ? b1_1 : b1_0;

    const int srow = tid >> 2;          // 0..127
    const int scol = (tid & 3) * 8;     // bf16 offset of 16B

    f32x4 acc[4][4];
#pragma unroll
    for (int ai = 0; ai < 4; ai++)
#pragma unroll
        for (int bj = 0; bj < 4; bj++) acc[ai][bj] = (f32x4){0.f,0.f,0.f,0.f};

    for (int kc = 0; kc < 16; kc++) {
        {
            const bf16* src = (kc < 8)
                ? Ahb + (size_t)srow*256 + kc*32 + scol
                : Ain + (size_t)srow*256 + (kc - 8)*32 + scol;
            gl_lds16(src, As + w*512);
        }
#pragma unroll
        for (int i = 0; i < 2; i++) {
            gl_lds16(Bw + (size_t)(j0 + i*128 + srow)*512 + kc*32 + scol,
                     Bs + i*4096 + w*512);
        }
        __syncthreads();
        short8 a[4], b[4];
#pragma unroll
        for (int ai = 0; ai < 4; ai++)
            a[ai] = *(const short8*)&As[(wr*64 + ai*16 + l15)*32 + lh*8];
#pragma unroll
        for (int bj = 0; bj < 4; bj++)
            b[bj] = *(const short8*)&Bs[(wc*64 + bj*16 + l15)*32 + lh*8];
#pragma unroll
        for (int ai = 0; ai < 4; ai++)
#pragma unroll
            for (int bj = 0; bj < 4; bj++)
                acc[ai][bj] = __builtin_amdgcn_mfma_f32_16x16x32_bf16(a[ai], b[bj], acc[ai][bj], 0, 0, 0);
        __syncthreads();
    }

#pragma unroll
    for (int ai = 0; ai < 4; ai++) {
#pragma unroll
        for (int bj = 0; bj < 4; bj++) {
#pragma unroll
            for (int i = 0; i < 4; i++) {
                long t = tok0 + wr*64 + ai*16 + lh*4 + i;
                int  j = j0 + wc*64 + bj*16 + l15;
                float v = acc[ai][bj][i] + b1[j];
                float s = v / (1.0f + __expf(-v));
                bf16 sb = f2bf(s);
                if (d == 0) {
                    *(bf16*)(x2b + (size_t)t*5120 + 2560 + j*2) = sb;
                } else {
                    if (j < 768) *(bf16*)(x1b + (size_t)t*3072 + 1536 + j*2) = sb;
                    else         hid1b[t*256 + (j - 768)] = sb;
                }
            }
        }
    }
}

// ---------------------------------------------------------------------------
// kmlp2: 512-thr / 8-wave blocks, 128x256 tile, BK=32, single-buffer,
// R4-exact sync. grid 768, LPT order: bids [0,256) = m1 (64 iters, launched
// first), [256,768) = m2 (32 iters). XCD swizzle within each class.
// slot m1: cols [0,256), K=2048 both degrees -> h_new (residual from hbf).
// slot m2_d: cols [256,512), K=1024 -> m2ws.
// hid0: x2 slot gap. hid1: x1 slot gap (kk<24) + hid1b ws (kk>=24).
// ---------------------------------------------------------------------------
__global__ __launch_bounds__(512) void kmlp2(const char* __restrict__ x1b,
                                             const char* __restrict__ x2b,
                                             const bf16* __restrict__ hid1b,
                                             const bf16* __restrict__ w2T,
                                             const float* __restrict__ b2_0,
                                             const float* __restrict__ b2_1,
                                             const bf16* __restrict__ hbf,
                                             bf16* __restrict__ m2ws,
                                             float* __restrict__ hout)
{
    __shared__ bf16 As[128*32];
    __shared__ bf16 Bs[256*32];
    const int tid = threadIdx.x;
    const int lane = tid & 63, w = tid >> 6;
    const int wr = w >> 2, wc = w & 3;
    const int lh = lane >> 4, l15 = lane & 15;

    // LPT decode: long m1 blocks first, then short m2 blocks.
    const int nb = blockIdx.x;
    int mtile, n0, dm2, nIter;
    bool is_m1;
    if (nb < 256) {
        int b2 = (nb & 7)*32 + (nb >> 3);       // bijective, q=32
        is_m1 = true;  mtile = b2; n0 = 0; dm2 = 0; nIter = 64;
    } else {
        int r = nb - 256;
        int b2 = (r & 7)*64 + (r >> 3);         // bijective, q=64
        is_m1 = false; mtile = b2 >> 1; n0 = 256; dm2 = b2 & 1; nIter = 32;
    }
    const long tok0 = (long)mtile * 128;

    const int srow = tid >> 2;
    const int scol = (tid & 3) * 8;

    f32x4 acc[4][4];
#pragma unroll
    for (int ai = 0; ai < 4; ai++)
#pragma unroll
        for (int bj = 0; bj < 4; bj++) acc[ai][bj] = (f32x4){0.f,0.f,0.f,0.f};

    for (int it = 0; it < nIter; it++) {
        const int d  = is_m1 ? (it >> 5) : dm2;
        const int kk = it & 31;
        {
            const bf16* src;
            if (d == 0)
                src = (const bf16*)(x2b + (size_t)(tok0 + srow)*5120 + 2560
                                    + kk*64 + (tid & 3)*16);
            else if (kk < 24)
                src = (const bf16*)(x1b + (size_t)(tok0 + srow)*3072 + 1536
                                    + kk*64 + (tid & 3)*16);
            else
                src = hid1b + (size_t)(tok0 + srow)*256 + (kk - 24)*32 + scol;
            gl_lds16(src, As + w*512);
        }
        const bf16* Bw = w2T + (size_t)d * TWOD * MLPD;
#pragma unroll
        for (int i = 0; i < 2; i++) {
            gl_lds16(Bw + (size_t)(n0 + i*128 + srow)*MLPD + kk*32 + scol,
                     Bs + i*4096 + w*512);
        }
        __syncthreads();
        short8 a[4], b[4];
#pragma unroll
        for (int ai = 0; ai < 4; ai++)
            a[ai] = *(const short8*)&As[(wr*64 + ai*16 + l15)*32 + lh*8];
#pragma unroll
        for (int bj = 0; bj < 4; bj++)
            b[bj] = *(const short8*)&Bs[(wc*64 + bj*16 + l15)*32 + lh*8];
#pragma unroll
        for (int ai = 0; ai < 4; ai++)
#pragma unroll
            for (int bj = 0; bj < 4; bj++)
                acc[ai][bj] = __builtin_amdgcn_mfma_f32_16x16x32_bf16(a[ai], b[bj], acc[ai][bj], 0, 0, 0);
        __syncthreads();
    }

#pragma unroll
    for (int ai = 0; ai < 4; ai++) {
#pragma unroll
        for (int bj = 0; bj < 4; bj++) {
#pragma unroll
            for (int i = 0; i < 4; i++) {
                long t = tok0 + wr*64 + ai*16 + lh*4 + i;
                int  n = n0 + wc*64 + bj*16 + l15;
                float v = acc[ai][bj][i];
                if (is_m1) {
                    v += b2_0[n] + b2_1[n];
                    hout[t*256 + n] = bf2f(hbf[t*256 + n]) + v;
                } else {
                    v += (dm2 ? b2_1 : b2_0)[n];
                    m2ws[(size_t)dm2 * BN * 256 + t*256 + (n - 256)] = f2bf(v);
                }
            }
        }
    }
}

// ---------------------------------------------------------------------------
extern "C" void kernel_launch(void* const* d_in, const int* in_sizes, int n_in,
                              void* d_out, int out_size, void* d_ws, size_t ws_size,
                              hipStream_t stream)
{
    const float* h     = (const float*)d_in[0];
    const float* x1    = (const float*)d_in[1];
    const float* x2    = (const float*)d_in[2];
    const float* proj1 = (const float*)d_in[3];
    const float* proj2 = (const float*)d_in[4];
    const float* pre1  = (const float*)d_in[5];
    const float* pre2  = (const float*)d_in[6];
    const float* w10   = (const float*)d_in[7];
    const float* b10   = (const float*)d_in[8];
    const float* w20   = (const float*)d_in[9];
    const float* b20   = (const float*)d_in[10];
    const float* w11   = (const float*)d_in[11];
    const float* b11   = (const float*)d_in[12];
    const float* w21   = (const float*)d_in[13];
    const float* b21   = (const float*)d_in[14];

    // ws (bf16 elems): preT[131072] projT[131072] w1T[1048576] w2T[1048576]
    //   hbf[8388608] invm2[16777216] hid1b[8388608] -> 35,913,728 = 68.5 MiB
    bf16* preT  = (bf16*)d_ws;
    bf16* projT = preT  + 131072;
    bf16* w1T   = projT + 131072;
    bf16* w2T   = w1T   + 1048576;
    bf16* hbf   = w2T   + 1048576;
    bf16* invm2 = hbf   + 8388608;   // inv (kxgi->kmlp1), then m2 (kmlp2->kxgm)
    bf16* hid1b = invm2 + 16777216;  // hid1 cols 768..1023
    if (ws_size < (size_t)35913728 * 2) return;

    float* hout  = (float*)d_out;
    float* x1out = hout + (size_t)8388608;   // 96 MiB region, 3072 B/token
    float* x2out = hout + (size_t)33554432;  // 160 MiB region, 5120 B/token
    char* x1b = (char*)x1out;  // slot: [xT1 1536B][hid1 j<768 1536B]
    char* x2b = (char*)x2out;  // slot: [xT2 2560B][hid0 2048B][pad 512B]

    kpre<<<9280, 256, 0, stream>>>(pre1, pre2, proj1, proj2, w10, w11, w20, w21,
                                   h, preT, w1T, w2T, hbf, x1, x1b, x2, x2b);
    kxgi<<<2048, 512, 0, stream>>>(x1b, x2b, preT, invm2);
    kmlp1<<<2048, 512, 0, stream>>>(hbf, invm2, w1T, b10, b11, x1b, x2b, hid1b);
    kmlp2<<<768, 512, 0, stream>>>(x1b, x2b, hid1b, w2T, b20, b21, hbf, invm2, hout);
    kxgm<<<2048, 512, 0, stream>>>(x1b, x2b, projT, invm2, x1out, x2out);
}

// Round 22
// 541.038 us; speedup vs baseline: 1.0577x; 1.0092x over previous
//
#include <hip/hip_runtime.h>
#include <hip/hip_bf16.h>

#define BN    32768
#define DD    256
#define MLPD  1024
#define TWOD  512

typedef __attribute__((ext_vector_type(8))) short short8;
typedef __attribute__((ext_vector_type(4))) float f32x4;

using bf16 = __hip_bfloat16;

__device__ __forceinline__ float bf2f(bf16 v){ return __bfloat162float(v); }
__device__ __forceinline__ bf16  f2bf(float v){ return __float2bfloat16(v); }

// async global->LDS, 16B per lane. LDS dest is wave-uniform base + lane*16.
__device__ __forceinline__ void gl_lds16(const bf16* g, bf16* l) {
    __builtin_amdgcn_global_load_lds(
        (const __attribute__((address_space(1))) void*)(g),
        (__attribute__((address_space(3))) void*)(l),
        16, 0, 0);
}

// ---------------------------------------------------------------------------
// kprep body: LDS-tiled transposes (64x64 f32 tiles) + hbf cast-copy.
// local bids [0,1088).
// ---------------------------------------------------------------------------
__device__ __forceinline__ void kprep_body(
    const float* __restrict__ pre1, const float* __restrict__ pre2,
    const float* __restrict__ proj1, const float* __restrict__ proj2,
    const float* __restrict__ w10, const float* __restrict__ w11,
    const float* __restrict__ w20, const float* __restrict__ w21,
    const float* __restrict__ h,
    bf16* __restrict__ preT, bf16* __restrict__ w1T, bf16* __restrict__ w2T,
    bf16* __restrict__ hbf, int bid, char* sm)
{
    float (*ft)[68] = (float (*)[68])sm;
    const int tid = threadIdx.x;
    const int row = tid >> 2;
    const int c4  = (tid & 3) * 16;

    auto do_tile = [&](const float* src, int srcld, int r0, int c0,
                       bf16* dst, int dstld) {
        const float* sp = src + (size_t)(r0 + row)*srcld + c0 + c4;
#pragma unroll
        for (int i = 0; i < 4; i++)
            *(float4*)&ft[row][c4 + i*4] = *(const float4*)(sp + i*4);
        __syncthreads();
        bf16* dp = dst + (size_t)(c0 + row)*dstld + r0 + c4;
        short8 v0, v1;
#pragma unroll
        for (int i = 0; i < 8; i++) {
            bf16 b = f2bf(ft[c4 + i][row]);     v0[i] = *(short*)&b;
            bf16 b2 = f2bf(ft[c4 + 8 + i][row]); v1[i] = *(short*)&b2;
        }
        *(short8*)dp = v0;
        *(short8*)(dp + 8) = v1;
    };

    if (bid < 256) {
        int d = bid >> 7, r = bid & 127;
        int kt = r >> 4, jt = r & 15;           // w1: [512][1024]
        do_tile(d ? w11 : w10, 1024, kt*64, jt*64,
                w1T + (size_t)d*524288, 512);
    } else if (bid < 512) {
        int r = bid - 256;
        int d = r >> 7; r &= 127;
        int kt = r >> 3, nt = r & 7;            // w2: [1024][512]
        do_tile(d ? w21 : w20, 512, kt*64, nt*64,
                w2T + (size_t)d*524288, 1024);
    } else if (bid < 576) {
        int r = bid - 512;
        int m = r >> 4; r &= 15;
        int kt = r >> 2, et = r & 3;            // pre/proj: [256][256]
        const float* src = (m == 0) ? pre1 : (m == 1) ? pre2
                         : (m == 2) ? proj1 : proj2;
        do_tile(src, 256, kt*64, et*64, preT + (size_t)m*65536, 256);
    } else {
        const long base = (long)(bid - 576) * 16384;
#pragma unroll
        for (int it = 0; it < 16; it++) {
            long o = base + it*1024 + tid*4;
            float4 v = *(const float4*)(h + o);
            short vv[4];
#pragma unroll
            for (int j = 0; j < 4; j++) {
                bf16 b = f2bf(((const float*)&v)[j]);
                vv[j] = *(short*)&b;
            }
            *(long*)(hbf + o) = *(long*)vv;
        }
    }
}

// ---------------------------------------------------------------------------
// kxT body: transpose x[t][d][m] f32 -> token-major bf16 planes in the
// token's own output slot. 8 tokens/block.
// ---------------------------------------------------------------------------
template<int M, int ST>
__device__ __forceinline__ void kxT_body(const float* __restrict__ x,
                                         char* __restrict__ outb,
                                         int bid, float* raw)
{
    const int tid = threadIdx.x;
    const long tok0 = (long)bid * 8;
    const float4* src = (const float4*)(x + tok0*256*M);
    const int n4 = (8*256*M)/4;
    for (int i = tid; i < n4; i += 256)
        ((float4*)raw)[i] = src[i];
    __syncthreads();
    const int nOut = 8*M*32;
    for (int i = tid; i < nOut; i += 256) {
        int d8 = i & 31;
        int tm = i >> 5;
        int t = tm / M, m = tm - t*M;
        short8 v;
#pragma unroll
        for (int j = 0; j < 8; j++) {
            bf16 bv = f2bf(raw[(t*256 + d8*8 + j)*M + m]);
            v[j] = *reinterpret_cast<short*>(&bv);
        }
        *(short8*)(outb + (size_t)(tok0 + t)*ST + m*512 + d8*16) = v;
    }
}

// ---------------------------------------------------------------------------
// kpre: merged kprep + kxT<3> + kxT<5>, LPT order (heaviest class first):
//   [0,4096)    kxT<5> (x2)
//   [4096,8192) kxT<3> (x1)
//   [8192,9280) kprep
// ---------------------------------------------------------------------------
__global__ __launch_bounds__(256) void kpre(
    const float* __restrict__ pre1, const float* __restrict__ pre2,
    const float* __restrict__ proj1, const float* __restrict__ proj2,
    const float* __restrict__ w10, const float* __restrict__ w11,
    const float* __restrict__ w20, const float* __restrict__ w21,
    const float* __restrict__ h,
    bf16* __restrict__ preT, bf16* __restrict__ w1T, bf16* __restrict__ w2T,
    bf16* __restrict__ hbf,
    const float* __restrict__ x1, char* __restrict__ x1b,
    const float* __restrict__ x2, char* __restrict__ x2b)
{
    __shared__ char sm[40960];   // union: ft 17.4K | raw3 24K | raw5 40K
    const int bid = blockIdx.x;
    if (bid < 4096)
        kxT_body<5, 5120>(x2, x2b, bid, (float*)sm);
    else if (bid < 8192)
        kxT_body<3, 3072>(x1, x1b, bid - 4096, (float*)sm);
    else
        kprep_body(pre1, pre2, proj1, proj2, w10, w11, w20, w21, h,
                   preT, w1T, w2T, hbf, bid - 8192, sm);
}

// ---------------------------------------------------------------------------
// kxg body: 32 tokens/block, 8 waves (wg = token-half, we = e-block).
// A = xT planes per half (gl_lds16), B staged once per chunk, shared halves.
// MOD=false: inv[t][e] = sqrt(sum_m acc^2).
// MOD=true : xout = bf16(x) + acc*m2 (phase A fold reads-only / full-drain
//            barrier / phase B writes-only; own-slot in-place safe).
// ---------------------------------------------------------------------------
template<int M, int ST, bool MOD>
__device__ __forceinline__ void kxg_body(const char* __restrict__ xtb,
                                         const bf16* __restrict__ Bmat,
                                         bf16* __restrict__ invp,
                                         const bf16* __restrict__ m2p,
                                         float* __restrict__ xout,
                                         int bid, bf16* As, bf16* Bs)
{
    const int tid = threadIdx.x;
    const int lane = tid & 63, w = tid >> 6;     // 8 waves
    const int wg = w >> 2, we = w & 3;           // token-half, e-block
    const int lh = lane >> 4, l15 = lane & 15;
    const long tok0 = (long)bid * 32;

    f32x4 acc[M][4];
#pragma unroll
    for (int m = 0; m < M; m++)
#pragma unroll
        for (int c = 0; c < 4; c++) acc[m][c] = (f32x4){0.f,0.f,0.f,0.f};

    for (int kc = 0; kc < 8; kc++) {
        for (int m = we; m < M; m += 4) {
            const char* src = xtb + (size_t)(tok0 + wg*16 + (lane >> 2))*ST
                              + m*512 + kc*64 + (lane & 3)*16;
            gl_lds16((const bf16*)src, As + (wg*M + m)*512);
        }
#pragma unroll
        for (int j = 0; j < 2; j++) {
            int row = (w*2 + j)*16 + (lane >> 2);
            gl_lds16(Bmat + row*256 + kc*32 + (lane & 3)*8,
                     Bs + (w*2 + j)*512);
        }
        __syncthreads();
        short8 a[M], b[4];
#pragma unroll
        for (int m = 0; m < M; m++)
            a[m] = *(const short8*)&As[(wg*M + m)*512 + l15*32 + lh*8];
#pragma unroll
        for (int ct = 0; ct < 4; ct++)
            b[ct] = *(const short8*)&Bs[(we*64 + ct*16 + l15)*32 + lh*8];
#pragma unroll
        for (int m = 0; m < M; m++)
#pragma unroll
            for (int ct = 0; ct < 4; ct++)
                acc[m][ct] = __builtin_amdgcn_mfma_f32_16x16x32_bf16(a[m], b[ct], acc[m][ct], 0, 0, 0);
        __syncthreads();
    }

    if constexpr (!MOD) {
#pragma unroll
        for (int ct = 0; ct < 4; ct++) {
#pragma unroll
            for (int i = 0; i < 4; i++) {
                long t = tok0 + wg*16 + lh*4 + i;
                int e = we*64 + ct*16 + l15;
                float s = 0.f;
#pragma unroll
                for (int m = 0; m < M; m++) { float p = acc[m][ct][i]; s += p*p; }
                invp[t*256 + e] = f2bf(sqrtf(s));
            }
        }
    } else {
        // phase A: fold residual (bf16 xT, L2-hot) + m2 scale. READS ONLY.
#pragma unroll
        for (int ct = 0; ct < 4; ct++) {
#pragma unroll
            for (int i = 0; i < 4; i++) {
                long t = tok0 + wg*16 + lh*4 + i;
                int e = we*64 + ct*16 + l15;
                float m2v = bf2f(m2p[t*256 + e]);
                const char* slot = xtb + (size_t)t*ST + e*2;
#pragma unroll
                for (int m = 0; m < M; m++) {
                    float xv = bf2f(*(const bf16*)(slot + m*512));
                    acc[m][ct][i] = xv + acc[m][ct][i]*m2v;
                }
            }
        }
        __syncthreads();
        // phase B: writes only
#pragma unroll
        for (int ct = 0; ct < 4; ct++) {
#pragma unroll
            for (int i = 0; i < 4; i++) {
                long t = tok0 + wg*16 + lh*4 + i;
                int e = we*64 + ct*16 + l15;
#pragma unroll
                for (int m = 0; m < M; m++) {
                    long gi = (t*256 + e)*(long)M + m;
                    xout[gi] = acc[m][ct][i];
                }
            }
        }
    }
}

// ---------------------------------------------------------------------------
// kxgi: merged inv pass, LPT: [0,1024) = x2 (M=5, heavier) first, rest x1.
// ---------------------------------------------------------------------------
__global__ __launch_bounds__(512) void kxgi(const char* __restrict__ x1b,
                                            const char* __restrict__ x2b,
                                            const bf16* __restrict__ preT,
                                            bf16* __restrict__ invm2)
{
    __shared__ bf16 As[2*5*512];
    __shared__ bf16 Bs[8192];
    const int bid = blockIdx.x;
    if (bid < 1024)
        kxg_body<5, 5120, false>(x2b, preT + 65536,
                                 invm2 + (size_t)BN*256, nullptr, nullptr,
                                 bid, As, Bs);
    else
        kxg_body<3, 3072, false>(x1b, preT, invm2, nullptr, nullptr,
                                 bid - 1024, As, Bs);
}

// ---------------------------------------------------------------------------
// kxgm: merged mod pass, LPT: [0,1024) = x2 (M=5, heavier) first, rest x1.
// ---------------------------------------------------------------------------
__global__ __launch_bounds__(512) void kxgm(const char* __restrict__ x1b,
                                            const char* __restrict__ x2b,
                                            const bf16* __restrict__ projT,
                                            const bf16* __restrict__ m2ws,
                                            float* __restrict__ x1out,
                                            float* __restrict__ x2out)
{
    __shared__ bf16 As[2*5*512];
    __shared__ bf16 Bs[8192];
    const int bid = blockIdx.x;
    if (bid < 1024)
        kxg_body<5, 5120, true>(x2b, projT + 65536, nullptr,
                                m2ws + (size_t)BN*256, x2out,
                                bid, As, Bs);
    else
        kxg_body<3, 3072, true>(x1b, projT, nullptr, m2ws, x1out,
                                bid - 1024, As, Bs);
}

// ---------------------------------------------------------------------------
// kmlp1: 512-thr / 8-wave blocks, 128x256 tile, BK=32, single-buffer LDS,
// R4-exact sync. C[t,j] over A=[hbf|inv_d] (K=512), B=w1T_d.
// Epilogue: bias+silu -> hid slots / hid1b.
// grid 2048 = 2 d x 256 mtile x 4 ntile, XCD swizzle q=256.
// ---------------------------------------------------------------------------
__global__ __launch_bounds__(512) void kmlp1(const bf16* __restrict__ hbf,
                                             const bf16* __restrict__ invws,
                                             const bf16* __restrict__ w1T,
                                             const float* __restrict__ b1_0,
                                             const float* __restrict__ b1_1,
                                             char* __restrict__ x1b,
                                             char* __restrict__ x2b,
                                             bf16* __restrict__ hid1b)
{
    __shared__ bf16 As[128*32];   // [128 t][32 k]
    __shared__ bf16 Bs[256*32];   // [256 j][32 k]
    const int tid = threadIdx.x;
    const int lane = tid & 63, w = tid >> 6;     // 8 waves
    const int wr = w >> 2, wc = w & 3;           // 2 row-blocks x 4 col-blocks
    const int lh = lane >> 4, l15 = lane & 15;

    const int bid   = ((blockIdx.x & 7) << 8) | (blockIdx.x >> 3);  // q=256
    const int d     = bid >> 10;
    const int r     = bid & 1023;
    const int mtile = r >> 2;
    const int ntile = r & 3;
    const long tok0 = (long)mtile * 128;
    const int  j0   = ntile * 256;

    const bf16* Ahb = hbf   + (size_t)tok0 * 256;
    const bf16* Ain = invws + (size_t)d * BN * 256 + (size_t)tok0 * 256;
    const bf16* Bw  = w1T   + (size_t)d * MLPD * TWOD;
    const float* b1 = d ? b1_1 : b1_0;

    const int srow = tid >> 2;          // 0..127
    const int scol = (tid & 3) * 8;     // bf16 offset of 16B

    f32x4 acc[4][4];
#pragma unroll
    for (int ai = 0; ai < 4; ai++)
#pragma unroll
        for (int bj = 0; bj < 4; bj++) acc[ai][bj] = (f32x4){0.f,0.f,0.f,0.f};

    for (int kc = 0; kc < 16; kc++) {
        {
            const bf16* src = (kc < 8)
                ? Ahb + (size_t)srow*256 + kc*32 + scol
                : Ain + (size_t)srow*256 + (kc - 8)*32 + scol;
            gl_lds16(src, As + w*512);
        }
#pragma unroll
        for (int i = 0; i < 2; i++) {
            gl_lds16(Bw + (size_t)(j0 + i*128 + srow)*512 + kc*32 + scol,
                     Bs + i*4096 + w*512);
        }
        __syncthreads();
        short8 a[4], b[4];
#pragma unroll
        for (int ai = 0; ai < 4; ai++)
            a[ai] = *(const short8*)&As[(wr*64 + ai*16 + l15)*32 + lh*8];
#pragma unroll
        for (int bj = 0; bj < 4; bj++)
            b[bj] = *(const short8*)&Bs[(wc*64 + bj*16 + l15)*32 + lh*8];
#pragma unroll
        for (int ai = 0; ai < 4; ai++)
#pragma unroll
            for (int bj = 0; bj < 4; bj++)
                acc[ai][bj] = __builtin_amdgcn_mfma_f32_16x16x32_bf16(a[ai], b[bj], acc[ai][bj], 0, 0, 0);
        __syncthreads();
    }

#pragma unroll
    for (int ai = 0; ai < 4; ai++) {
#pragma unroll
        for (int bj = 0; bj < 4; bj++) {
#pragma unroll
            for (int i = 0; i < 4; i++) {
                long t = tok0 + wr*64 + ai*16 + lh*4 + i;
                int  j = j0 + wc*64 + bj*16 + l15;
                float v = acc[ai][bj][i] + b1[j];
                float s = v / (1.0f + __expf(-v));
                bf16 sb = f2bf(s);
                if (d == 0) {
                    *(bf16*)(x2b + (size_t)t*5120 + 2560 + j*2) = sb;
                } else {
                    if (j < 768) *(bf16*)(x1b + (size_t)t*3072 + 1536 + j*2) = sb;
                    else         hid1b[t*256 + (j - 768)] = sb;
                }
            }
        }
    }
}

// ---------------------------------------------------------------------------
// kmlp2: 512-thr / 8-wave blocks, 128x256 tile, BK=32, single-buffer,
// R4-exact sync. grid 768, LPT order: bids [0,256) = m1 (64 iters, launched
// first), [256,768) = m2 (32 iters). XCD swizzle within each class.
// slot m1: cols [0,256), K=2048 both degrees -> h_new (residual from hbf).
// slot m2_d: cols [256,512), K=1024 -> m2ws.
// hid0: x2 slot gap. hid1: x1 slot gap (kk<24) + hid1b ws (kk>=24).
// ---------------------------------------------------------------------------
__global__ __launch_bounds__(512) void kmlp2(const char* __restrict__ x1b,
                                             const char* __restrict__ x2b,
                                             const bf16* __restrict__ hid1b,
                                             const bf16* __restrict__ w2T,
                                             const float* __restrict__ b2_0,
                                             const float* __restrict__ b2_1,
                                             const bf16* __restrict__ hbf,
                                             bf16* __restrict__ m2ws,
                                             float* __restrict__ hout)
{
    __shared__ bf16 As[128*32];
    __shared__ bf16 Bs[256*32];
    const int tid = threadIdx.x;
    const int lane = tid & 63, w = tid >> 6;
    const int wr = w >> 2, wc = w & 3;
    const int lh = lane >> 4, l15 = lane & 15;

    // LPT decode: long m1 blocks first, then short m2 blocks.
    const int nb = blockIdx.x;
    int mtile, n0, dm2, nIter;
    bool is_m1;
    if (nb < 256) {
        int b2 = (nb & 7)*32 + (nb >> 3);       // bijective, q=32
        is_m1 = true;  mtile = b2; n0 = 0; dm2 = 0; nIter = 64;
    } else {
        int r = nb - 256;
        int b2 = (r & 7)*64 + (r >> 3);         // bijective, q=64
        is_m1 = false; mtile = b2 >> 1; n0 = 256; dm2 = b2 & 1; nIter = 32;
    }
    const long tok0 = (long)mtile * 128;

    const int srow = tid >> 2;
    const int scol = (tid & 3) * 8;

    f32x4 acc[4][4];
#pragma unroll
    for (int ai = 0; ai < 4; ai++)
#pragma unroll
        for (int bj = 0; bj < 4; bj++) acc[ai][bj] = (f32x4){0.f,0.f,0.f,0.f};

    for (int it = 0; it < nIter; it++) {
        const int d  = is_m1 ? (it >> 5) : dm2;
        const int kk = it & 31;
        {
            const bf16* src;
            if (d == 0)
                src = (const bf16*)(x2b + (size_t)(tok0 + srow)*5120 + 2560
                                    + kk*64 + (tid & 3)*16);
            else if (kk < 24)
                src = (const bf16*)(x1b + (size_t)(tok0 + srow)*3072 + 1536
                                    + kk*64 + (tid & 3)*16);
            else
                src = hid1b + (size_t)(tok0 + srow)*256 + (kk - 24)*32 + scol;
            gl_lds16(src, As + w*512);
        }
        const bf16* Bw = w2T + (size_t)d * TWOD * MLPD;
#pragma unroll
        for (int i = 0; i < 2; i++) {
            gl_lds16(Bw + (size_t)(n0 + i*128 + srow)*MLPD + kk*32 + scol,
                     Bs + i*4096 + w*512);
        }
        __syncthreads();
        short8 a[4], b[4];
#pragma unroll
        for (int ai = 0; ai < 4; ai++)
            a[ai] = *(const short8*)&As[(wr*64 + ai*16 + l15)*32 + lh*8];
#pragma unroll
        for (int bj = 0; bj < 4; bj++)
            b[bj] = *(const short8*)&Bs[(wc*64 + bj*16 + l15)*32 + lh*8];
#pragma unroll
        for (int ai = 0; ai < 4; ai++)
#pragma unroll
            for (int bj = 0; bj < 4; bj++)
                acc[ai][bj] = __builtin_amdgcn_mfma_f32_16x16x32_bf16(a[ai], b[bj], acc[ai][bj], 0, 0, 0);
        __syncthreads();
    }

#pragma unroll
    for (int ai = 0; ai < 4; ai++) {
#pragma unroll
        for (int bj = 0; bj < 4; bj++) {
#pragma unroll
            for (int i = 0; i < 4; i++) {
                long t = tok0 + wr*64 + ai*16 + lh*4 + i;
                int  n = n0 + wc*64 + bj*16 + l15;
                float v = acc[ai][bj][i];
                if (is_m1) {
                    v += b2_0[n] + b2_1[n];
                    hout[t*256 + n] = bf2f(hbf[t*256 + n]) + v;
                } else {
                    v += (dm2 ? b2_1 : b2_0)[n];
                    m2ws[(size_t)dm2 * BN * 256 + t*256 + (n - 256)] = f2bf(v);
                }
            }
        }
    }
}

// ---------------------------------------------------------------------------
extern "C" void kernel_launch(void* const* d_in, const int* in_sizes, int n_in,
                              void* d_out, int out_size, void* d_ws, size_t ws_size,
                              hipStream_t stream)
{
    const float* h     = (const float*)d_in[0];
    const float* x1    = (const float*)d_in[1];
    const float* x2    = (const float*)d_in[2];
    const float* proj1 = (const float*)d_in[3];
    const float* proj2 = (const float*)d_in[4];
    const float* pre1  = (const float*)d_in[5];
    const float* pre2  = (const float*)d_in[6];
    const float* w10   = (const float*)d_in[7];
    const float* b10   = (const float*)d_in[8];
    const float* w20   = (const float*)d_in[9];
    const float* b20   = (const float*)d_in[10];
    const float* w11   = (const float*)d_in[11];
    const float* b11   = (const float*)d_in[12];
    const float* w21   = (const float*)d_in[13];
    const float* b21   = (const float*)d_in[14];

    // ws (bf16 elems): preT[131072] projT[131072] w1T[1048576] w2T[1048576]
    //   hbf[8388608] invm2[16777216] hid1b[8388608] -> 35,913,728 = 68.5 MiB
    bf16* preT  = (bf16*)d_ws;
    bf16* projT = preT  + 131072;
    bf16* w1T   = projT + 131072;
    bf16* w2T   = w1T   + 1048576;
    bf16* hbf   = w2T   + 1048576;
    bf16* invm2 = hbf   + 8388608;   // inv (kxgi->kmlp1), then m2 (kmlp2->kxgm)
    bf16* hid1b = invm2 + 16777216;  // hid1 cols 768..1023
    if (ws_size < (size_t)35913728 * 2) return;

    float* hout  = (float*)d_out;
    float* x1out = hout + (size_t)8388608;   // 96 MiB region, 3072 B/token
    float* x2out = hout + (size_t)33554432;  // 160 MiB region, 5120 B/token
    char* x1b = (char*)x1out;  // slot: [xT1 1536B][hid1 j<768 1536B]
    char* x2b = (char*)x2out;  // slot: [xT2 2560B][hid0 2048B][pad 512B]

    kpre<<<9280, 256, 0, stream>>>(pre1, pre2, proj1, proj2, w10, w11, w20, w21,
                                   h, preT, w1T, w2T, hbf, x1, x1b, x2, x2b);
    kxgi<<<2048, 512, 0, stream>>>(x1b, x2b, preT, invm2);
    kmlp1<<<2048, 512, 0, stream>>>(hbf, invm2, w1T, b10, b11, x1b, x2b, hid1b);
    kmlp2<<<768, 512, 0, stream>>>(x1b, x2b, hid1b, w2T, b20, b21, hbf, invm2, hout);
    kxgm<<<2048, 512, 0, stream>>>(x1b, x2b, projT, invm2, x1out, x2out);
}